// Round 4
// baseline (345.767 us; speedup 1.0000x reference)
//
#include <hip/hip_runtime.h>
#include <hip/hip_bf16.h>
#include <stdint.h>

// DispersiveLoss: B=1024 rows, D=65536.
// R4: symmetric Gram — 10 upper-tri 256x256 tiles, work linearized over
// (tile,K) into 256 equal blocks of 2560 K (40 BK-tiles); 8-phase
// counted-vmcnt schedule (m201 structure) with race-free staggered staging;
// each segment writes a full 256x256 fp32 partial (266 slots, non-atomic).
// Reduction gathers ~26 partials per tile for i<j cells only.

#define NROWS 1024
#define KDIM  65536
#define BK    64
#define KTPT  1024        // K-tiles (BK) per tile column: 65536/64
#define KTPB  40          // K-tiles per block: 10*1024/256
#define PARTN 266         // 256 block partials + 10 tile-crossing extras

typedef __attribute__((ext_vector_type(8))) short  s16x8;
typedef __attribute__((ext_vector_type(4))) float  f32x4;

#define AS1 __attribute__((address_space(1)))
#define AS3 __attribute__((address_space(3)))

__device__ __forceinline__ ushort f2bf(float f) {
  uint32_t u = __float_as_uint(f);
  return (ushort)((u + 0x7fffu + ((u >> 16) & 1u)) >> 16);  // RNE bf16
}

// ---- fused: row sum-of-squares -> inv_norm, plus raw fp32 -> bf16 cast ----
__global__ void k_prep(const float* __restrict__ z, ushort* __restrict__ zb,
                       float* __restrict__ inv_norm) {
  const int row = blockIdx.x;
  const float4* zr = (const float4*)(z + (size_t)row * KDIM);
  ushort* br = zb + (size_t)row * KDIM;
  float ss = 0.f;
  for (int i = threadIdx.x; i < KDIM / 4; i += blockDim.x) {
    const float4 v = zr[i];
    ss += v.x * v.x + v.y * v.y + v.z * v.z + v.w * v.w;
    ushort4 o;
    o.x = f2bf(v.x); o.y = f2bf(v.y); o.z = f2bf(v.z); o.w = f2bf(v.w);
    ((ushort4*)br)[i] = o;
  }
  for (int off = 32; off; off >>= 1) ss += __shfl_down(ss, off, 64);
  __shared__ float part[4];
  const int lane = threadIdx.x & 63, w = threadIdx.x >> 6;
  if (lane == 0) part[w] = ss;
  __syncthreads();
  if (threadIdx.x == 0) {
    const float t = part[0] + part[1] + part[2] + part[3];
    inv_norm[row] = 1.f / fmaxf(sqrtf(t), 1e-12f);
  }
}

// ---- 256^2 8-phase symmetric Gram, segmented K ----
// LDS (bytes): A[buf][half] = buf*32768 + half*16384 ; B = 65536 + same.
// Swizzle within a 128x64-bf16 half: P = L ^ (((L>>9)&1)<<5)  (involution).
__global__ __launch_bounds__(512, 1)
void k_gram8(const ushort* __restrict__ zb, float* __restrict__ pbuf) {
  extern __shared__ char smem[];
  const int tid  = threadIdx.x;
  const int lane = tid & 63;
  const int wid  = tid >> 6;
  const int wr   = wid >> 2;     // 0..1  (M half)
  const int wc   = wid & 3;      // 0..3  (N quarter)

  const int b   = blockIdx.x;         // 0..255
  const int w0  = b * KTPB;           // global K-tile work index
  const int t1  = w0 >> 10;           // tile id (w0 / KTPT)
  const int kt0 = w0 & (KTPT - 1);
  const int n1  = min(KTPB, KTPT - kt0);
  const int nseg = (n1 < KTPB) ? 2 : 1;

  const uint32_t laneRB  = (uint32_t)(lane & 15) * 128u + (uint32_t)(lane >> 4) * 16u;
  const uint32_t aBase   = (uint32_t)wr * 16384u;
  const uint32_t bBase   = 65536u + (uint32_t)(wc >> 1) * 16384u;
  const uint32_t bRowOff = (uint32_t)(wc & 1) * 64u * 128u;

  for (int seg = 0; seg < nseg; ++seg) {
    const int t    = (seg == 0) ? t1 : t1 + 1;
    const int kts  = (seg == 0) ? kt0 : 0;
    const int cnt  = (seg == 0) ? n1  : KTPB - n1;   // >= 8 always
    const int pidx = (seg == 0) ? b   : 256 + t;

    // tile id -> (tm, tn), upper-tri row-major enumeration of 4x4
    const int tm   = (t < 4) ? 0 : (t < 7) ? 1 : (t < 9) ? 2 : 3;
    const int tbase = 4 * tm - ((tm * (tm - 1)) >> 1);
    const int tn   = t - tbase + tm;

    const ushort* gA = zb + (size_t)(tm * 256) * KDIM;
    const ushort* gB = zb + (size_t)(tn * 256) * KDIM;

    // stage one 128x64 half-tile (16 KB): 2 x global_load_lds(16B)/thread.
    // LDS dest linear (wave-uniform + lane*16); global src pre-swizzled.
    auto stage_half = [&](const ushort* halfPanel, uint32_t ldsHalfBase, int ktAbs) {
#pragma unroll
      for (int q = 0; q < 2; q++) {
        const uint32_t P = q * 8192u + (uint32_t)tid * 16u;
        const uint32_t L = P ^ (((P >> 9) & 1u) << 5);
        __builtin_amdgcn_global_load_lds(
            (const AS1 void*)((const char*)halfPanel + (size_t)(L >> 7) * (KDIM * 2)
                              + (L & 127u) + (size_t)ktAbs * (BK * 2)),
            (AS3 void*)(smem + ldsHalfBase + P), 16, 0, 0);
      }
    };
    auto rdA = [&](uint32_t bo, int mi, int kk) -> s16x8 {
      uint32_t L = laneRB + (uint32_t)mi * 2048u + (uint32_t)kk * 64u;
      uint32_t P = L ^ (((L >> 9) & 1u) << 5);
      return *(const s16x8*)(smem + aBase + bo + P);
    };
    auto rdB = [&](uint32_t bo, int ni, int kk) -> s16x8 {
      uint32_t L = bRowOff + laneRB + (uint32_t)ni * 2048u + (uint32_t)kk * 64u;
      uint32_t P = L ^ (((L >> 9) & 1u) << 5);
      return *(const s16x8*)(smem + bBase + bo + P);
    };

    f32x4 acc[8][4];
#pragma unroll
    for (int m = 0; m < 8; m++)
#pragma unroll
      for (int n = 0; n < 4; n++) acc[m][n] = (f32x4){0.f, 0.f, 0.f, 0.f};

    // prologue: tiles kts+0 -> buf0, kts+1 -> buf1 (cnt >= 8 guarantees both)
#pragma unroll
    for (int kt = 0; kt < 2; kt++) {
      const uint32_t bo = (uint32_t)kt * 32768u;
      stage_half(gB,              65536u + bo,          kts + kt);
      stage_half(gB + 128 * KDIM, 65536u + bo + 16384u, kts + kt);
      stage_half(gA,              bo,                   kts + kt);
      stage_half(gA + 128 * KDIM, bo + 16384u,          kts + kt);
    }
    asm volatile("s_waitcnt vmcnt(8)" ::: "memory");  // tile kts+0 landed
    __builtin_amdgcn_s_barrier();

    s16x8 a[8][2], bb[4][2];
    for (int T = 0; T < cnt; ++T) {
      const uint32_t bo = (uint32_t)(T & 1) * 32768u;
      const int S = T + 2;
      const bool st = (S < cnt);
      const int ktS = kts + S;

      // phase 0: read B(8) + A m0,m1 ; no staging (race-free discipline)
#pragma unroll
      for (int n = 0; n < 4; n++) { bb[n][0] = rdB(bo, n, 0); bb[n][1] = rdB(bo, n, 1); }
#pragma unroll
      for (int m = 0; m < 2; m++) { a[m][0] = rdA(bo, m, 0); a[m][1] = rdA(bo, m, 1); }
      __builtin_amdgcn_s_barrier();
      __builtin_amdgcn_s_setprio(1);
#pragma unroll
      for (int m = 0; m < 2; m++)
#pragma unroll
        for (int n = 0; n < 4; n++) {
          acc[m][n] = __builtin_amdgcn_mfma_f32_16x16x32_bf16(a[m][0], bb[n][0], acc[m][n], 0, 0, 0);
          acc[m][n] = __builtin_amdgcn_mfma_f32_16x16x32_bf16(a[m][1], bb[n][1], acc[m][n], 0, 0, 0);
        }
      __builtin_amdgcn_s_setprio(0);
      __builtin_amdgcn_s_barrier();

      // phase 1: read A m2..7 ; stage B0',B1' (B fully read in phase 0)
#pragma unroll
      for (int m = 2; m < 8; m++) { a[m][0] = rdA(bo, m, 0); a[m][1] = rdA(bo, m, 1); }
      if (st) {
        stage_half(gB,              65536u + bo,          ktS);
        stage_half(gB + 128 * KDIM, 65536u + bo + 16384u, ktS);
      }
      __builtin_amdgcn_s_barrier();
      __builtin_amdgcn_s_setprio(1);
#pragma unroll
      for (int m = 2; m < 4; m++)
#pragma unroll
        for (int n = 0; n < 4; n++) {
          acc[m][n] = __builtin_amdgcn_mfma_f32_16x16x32_bf16(a[m][0], bb[n][0], acc[m][n], 0, 0, 0);
          acc[m][n] = __builtin_amdgcn_mfma_f32_16x16x32_bf16(a[m][1], bb[n][1], acc[m][n], 0, 0, 0);
        }
      __builtin_amdgcn_s_setprio(0);
      __builtin_amdgcn_s_barrier();

      // phase 2: stage A0' (A fully read by end of phase 1)
      if (st) stage_half(gA, bo, ktS);
      __builtin_amdgcn_s_barrier();
      __builtin_amdgcn_s_setprio(1);
#pragma unroll
      for (int m = 4; m < 6; m++)
#pragma unroll
        for (int n = 0; n < 4; n++) {
          acc[m][n] = __builtin_amdgcn_mfma_f32_16x16x32_bf16(a[m][0], bb[n][0], acc[m][n], 0, 0, 0);
          acc[m][n] = __builtin_amdgcn_mfma_f32_16x16x32_bf16(a[m][1], bb[n][1], acc[m][n], 0, 0, 0);
        }
      __builtin_amdgcn_s_setprio(0);
      __builtin_amdgcn_s_barrier();

      // phase 3: stage A1' ; counted vmcnt (8 in flight = tile S), end barrier
      if (st) stage_half(gA + 128 * KDIM, bo + 16384u, ktS);
      __builtin_amdgcn_s_barrier();
      __builtin_amdgcn_s_setprio(1);
#pragma unroll
      for (int m = 6; m < 8; m++)
#pragma unroll
        for (int n = 0; n < 4; n++) {
          acc[m][n] = __builtin_amdgcn_mfma_f32_16x16x32_bf16(a[m][0], bb[n][0], acc[m][n], 0, 0, 0);
          acc[m][n] = __builtin_amdgcn_mfma_f32_16x16x32_bf16(a[m][1], bb[n][1], acc[m][n], 0, 0, 0);
        }
      __builtin_amdgcn_s_setprio(0);
      if (st) { asm volatile("s_waitcnt vmcnt(8)" ::: "memory"); }  // tile T+1 landed
      else    { asm volatile("s_waitcnt vmcnt(0)" ::: "memory"); }
      __builtin_amdgcn_s_barrier();
    }

    // epilogue: tile-local 256x256 partial, non-atomic full write
    // C/D layout (m89): col = lane&15, row = (lane>>4)*4 + reg
    float* outp = pbuf + (size_t)pidx * 65536;
    const int r0 = wr * 128 + ((lane >> 4) << 2);
    const int c0 = wc * 64 + (lane & 15);
#pragma unroll
    for (int m = 0; m < 8; m++)
#pragma unroll
      for (int n = 0; n < 4; n++)
#pragma unroll
        for (int rg = 0; rg < 4; rg++)
          outp[(size_t)(r0 + m * 16 + rg) * 256 + (c0 + n * 16)] = acc[m][n][rg];
  }
}

// helpers: tile id from (ti<=tj); partial range of tile t
__device__ __forceinline__ int tile_id(int ti, int tj) {
  return 4 * ti - ((ti * (ti - 1)) >> 1) + (tj - ti);
}

// ---- diag_n[i] = g[i][i] * inv_i^2 ----
__global__ void k_diag(const float* __restrict__ pbuf, const float* __restrict__ inv_norm,
                       float* __restrict__ diag) {
  const int i = blockIdx.x * 256 + threadIdx.x;
  const int ti = i >> 8;
  const int t = tile_id(ti, ti);
  const int b_lo = (KTPT * t + KTPB - 1) / KTPB;
  const int b_hi = (KTPT * (t + 1) + KTPB - 1) / KTPB - 1;
  const bool extra = ((KTPT * t) % KTPB) != 0;
  const int off = (i & 255) * 257;   // (i&255)*256 + (i&255)
  float s = 0.f;
  for (int p = b_lo; p <= b_hi; ++p) s += pbuf[(size_t)p * 65536 + off];
  if (extra) s += pbuf[(size_t)(256 + t) * 65536 + off];
  const float w = inv_norm[i];
  diag[i] = s * w * w;
}

// ---- accum = sum_{i<j} exp(-max(d_i + d_j - 2 g_ij inv_i inv_j, 0)) ----
__global__ void k_expsum(const float* __restrict__ pbuf, const float* __restrict__ inv_norm,
                         const float* __restrict__ diag, float* __restrict__ accum) {
  const int gid = blockIdx.x * 256 + threadIdx.x;
  const int e0 = gid * 4;
  const int i  = e0 >> 10;
  const int j0 = e0 & 1023;
  const int ti = i >> 8, tj = j0 >> 8;
  float s = 0.f;
  if (tj >= ti && j0 + 3 > i) {
    const int t = tile_id(ti, tj);
    const int b_lo = (KTPT * t + KTPB - 1) / KTPB;
    const int b_hi = (KTPT * (t + 1) + KTPB - 1) / KTPB - 1;
    const bool extra = ((KTPT * t) % KTPB) != 0;
    const int off = (i & 255) * 256 + (j0 & 255);
    float gx = 0.f, gy = 0.f, gz = 0.f, gw = 0.f;
    for (int p = b_lo; p <= b_hi; ++p) {
      const float4 v = *(const float4*)(pbuf + (size_t)p * 65536 + off);
      gx += v.x; gy += v.y; gz += v.z; gw += v.w;
    }
    if (extra) {
      const float4 v = *(const float4*)(pbuf + (size_t)(256 + t) * 65536 + off);
      gx += v.x; gy += v.y; gz += v.z; gw += v.w;
    }
    const float wi = inv_norm[i];
    const float di = diag[i];
    const float4 wj = *(const float4*)(inv_norm + j0);
    const float4 dj = *(const float4*)(diag + j0);
    float gn, d2;
    gn = gx * wi * wj.x; d2 = fmaxf(di + dj.x - 2.f * gn, 0.f); if (i < j0 + 0) s += expf(-d2);
    gn = gy * wi * wj.y; d2 = fmaxf(di + dj.y - 2.f * gn, 0.f); if (i < j0 + 1) s += expf(-d2);
    gn = gz * wi * wj.z; d2 = fmaxf(di + dj.z - 2.f * gn, 0.f); if (i < j0 + 2) s += expf(-d2);
    gn = gw * wi * wj.w; d2 = fmaxf(di + dj.w - 2.f * gn, 0.f); if (i < j0 + 3) s += expf(-d2);
  }
  for (int off = 32; off; off >>= 1) s += __shfl_down(s, off, 64);
  __shared__ float part[4];
  const int lane = threadIdx.x & 63, w = threadIdx.x >> 6;
  if (lane == 0) part[w] = s;
  __syncthreads();
  if (threadIdx.x == 0) atomicAdd(accum, part[0] + part[1] + part[2] + part[3]);
}

__global__ void k_final(const float* __restrict__ accum, float* __restrict__ out) {
  const float n_pairs = (float)NROWS * (float)(NROWS - 1) * 0.5f;  // i<j count
  out[0] = 0.25f * logf(accum[0] / n_pairs);
}

extern "C" void kernel_launch(void* const* d_in, const int* in_sizes, int n_in,
                              void* d_out, int out_size, void* d_ws, size_t ws_size,
                              hipStream_t stream) {
  const float* z = (const float*)d_in[0];
  float* out = (float*)d_out;
  char* ws = (char*)d_ws;

  // layout: inv_norm 4KB | diag 4KB | accum | ... | pbuf 68MB | zb 128MB  (~204MB, ws ~1GB)
  float*  inv_norm = (float*)(ws);
  float*  diag     = (float*)(ws + 4096);
  float*  accum    = (float*)(ws + 8192);
  float*  pbuf     = (float*)(ws + 65536);
  ushort* zbuf     = (ushort*)(ws + 65536 + (size_t)PARTN * 65536 * sizeof(float));

  hipMemsetAsync(accum, 0, sizeof(float), stream);

  k_prep<<<NROWS, 256, 0, stream>>>(z, zbuf, inv_norm);

  hipFuncSetAttribute(reinterpret_cast<const void*>(&k_gram8),
                      hipFuncAttributeMaxDynamicSharedMemorySize, 131072);
  k_gram8<<<256, 512, 131072, stream>>>(zbuf, pbuf);

  k_diag<<<NROWS / 256, 256, 0, stream>>>(pbuf, inv_norm, diag);
  k_expsum<<<(NROWS * NROWS / 4) / 256, 256, 0, stream>>>(pbuf, inv_norm, diag, accum);
  k_final<<<1, 1, 0, stream>>>(accum, out);
}

// Round 5
// 326.371 us; speedup vs baseline: 1.0594x; 1.0594x over previous
//
#include <hip/hip_runtime.h>
#include <hip/hip_bf16.h>
#include <stdint.h>

// DispersiveLoss: B=1024 rows, D=65536.
// R5: fix R4's two regressions:
//  (1) register spills (WRITE_SIZE 186MB vs 68MB expected) -> A fragments
//      read per-phase (16 VGPR transient) instead of 6-row preload; live set
//      ~ acc128 + B32 + addr, under the 256/wave budget at 512 threads.
//  (2) ineffective 1-bit LDS swizzle (7.9M bank conflicts) -> 3-bit XOR
//      swizzle P = L ^ (((L>>7)&7)<<4): full 8-slot spread, involution,
//      compatible with linear-dest global_load_lds + pre-swizzled source.
// Staging schedule (race-free, >=1 barrier between last read and overwrite):
//  p0: stage A0(T+1) into idle buf | p1: A1(T+1) | p2: B0(T+2) into cur buf
//  (B fully read at p0) | p3: B1(T+2); end-of-iter vmcnt(4).

#define NROWS 1024
#define KDIM  65536
#define BK    64
#define KTPT  1024        // K-tiles per tile: 65536/64
#define KTPB  40          // K-tiles per block: 10*1024/256
#define PARTN 266         // 256 block partials + 10 tile-crossing extras

typedef __attribute__((ext_vector_type(8))) short  s16x8;
typedef __attribute__((ext_vector_type(4))) float  f32x4;

#define AS1 __attribute__((address_space(1)))
#define AS3 __attribute__((address_space(3)))

__device__ __forceinline__ ushort f2bf(float f) {
  uint32_t u = __float_as_uint(f);
  return (ushort)((u + 0x7fffu + ((u >> 16) & 1u)) >> 16);  // RNE bf16
}

// ---- fused: row sum-of-squares -> inv_norm, plus raw fp32 -> bf16 cast ----
__global__ void k_prep(const float* __restrict__ z, ushort* __restrict__ zb,
                       float* __restrict__ inv_norm) {
  const int row = blockIdx.x;
  const float4* zr = (const float4*)(z + (size_t)row * KDIM);
  ushort* br = zb + (size_t)row * KDIM;
  float ss = 0.f;
  for (int i = threadIdx.x; i < KDIM / 4; i += blockDim.x) {
    const float4 v = zr[i];
    ss += v.x * v.x + v.y * v.y + v.z * v.z + v.w * v.w;
    ushort4 o;
    o.x = f2bf(v.x); o.y = f2bf(v.y); o.z = f2bf(v.z); o.w = f2bf(v.w);
    ((ushort4*)br)[i] = o;
  }
  for (int off = 32; off; off >>= 1) ss += __shfl_down(ss, off, 64);
  __shared__ float part[4];
  const int lane = threadIdx.x & 63, w = threadIdx.x >> 6;
  if (lane == 0) part[w] = ss;
  __syncthreads();
  if (threadIdx.x == 0) {
    const float t = part[0] + part[1] + part[2] + part[3];
    inv_norm[row] = 1.f / fmaxf(sqrtf(t), 1e-12f);
  }
}

// ---- 256^2 8-phase symmetric Gram, segmented K ----
// LDS (bytes): A[buf][half] = buf*32768 + half*16384 ; B = 65536 + same.
// Swizzle within a 128x64-bf16 half: P = L ^ (((L>>7)&7)<<4).
__global__ __launch_bounds__(512, 1)
void k_gram8(const ushort* __restrict__ zb, float* __restrict__ pbuf) {
  extern __shared__ char smem[];
  const int tid  = threadIdx.x;
  const int lane = tid & 63;
  const int wid  = tid >> 6;
  const int wr   = wid >> 2;     // 0..1  (M half)
  const int wc   = wid & 3;      // 0..3  (N quarter)

  const int b   = blockIdx.x;         // 0..255
  const int w0  = b * KTPB;
  const int t1  = w0 >> 10;
  const int kt0 = w0 & (KTPT - 1);
  const int n1  = min(KTPB, KTPT - kt0);
  const int nseg = (n1 < KTPB) ? 2 : 1;

  const uint32_t laneRB  = (uint32_t)(lane & 15) * 128u + (uint32_t)(lane >> 4) * 16u;
  const uint32_t aBase   = (uint32_t)wr * 16384u;
  const uint32_t bBase   = 65536u + (uint32_t)(wc >> 1) * 16384u;
  const uint32_t bRowOff = (uint32_t)(wc & 1) * 8192u;   // 64 rows * 128 B

  for (int seg = 0; seg < nseg; ++seg) {
    const int t    = (seg == 0) ? t1 : t1 + 1;
    const int kts  = (seg == 0) ? kt0 : 0;
    const int cnt  = (seg == 0) ? n1  : KTPB - n1;   // >= 16 always
    const int pidx = (seg == 0) ? b   : 256 + t;

    const int tm = (t < 4) ? 0 : (t < 7) ? 1 : (t < 9) ? 2 : 3;
    const int tbase = 4 * tm - ((tm * (tm - 1)) >> 1);
    const int tn = t - tbase + tm;

    const ushort* gA = zb + (size_t)(tm * 256) * KDIM;
    const ushort* gB = zb + (size_t)(tn * 256) * KDIM;

    // stage one 128x64 half-tile (16 KB): 2 x global_load_lds(16B)/thread.
    // LDS dest linear; global source pre-swizzled (involution).
    auto stage_half = [&](const ushort* halfPanel, uint32_t ldsHalfBase, int ktAbs) {
#pragma unroll
      for (int q = 0; q < 2; q++) {
        const uint32_t P = q * 8192u + (uint32_t)tid * 16u;
        const uint32_t L = P ^ (((P >> 7) & 7u) << 4);
        __builtin_amdgcn_global_load_lds(
            (const AS1 void*)((const char*)halfPanel + (size_t)(L >> 7) * (KDIM * 2)
                              + (L & 127u) + (size_t)ktAbs * (BK * 2)),
            (AS3 void*)(smem + ldsHalfBase + P), 16, 0, 0);
      }
    };
    auto rdA = [&](uint32_t bo, int mi, int kk) -> s16x8 {
      uint32_t L = laneRB + (uint32_t)mi * 2048u + (uint32_t)kk * 64u;
      uint32_t P = L ^ (((L >> 7) & 7u) << 4);
      return *(const s16x8*)(smem + aBase + bo + P);
    };
    auto rdB = [&](uint32_t bo, int ni, int kk) -> s16x8 {
      uint32_t L = bRowOff + laneRB + (uint32_t)ni * 2048u + (uint32_t)kk * 64u;
      uint32_t P = L ^ (((L >> 7) & 7u) << 4);
      return *(const s16x8*)(smem + bBase + bo + P);
    };

    f32x4 acc[8][4];
#pragma unroll
    for (int m = 0; m < 8; m++)
#pragma unroll
      for (int n = 0; n < 4; n++) acc[m][n] = (f32x4){0.f, 0.f, 0.f, 0.f};

    // prologue: tile kts -> buf0 (all 4 halves), tile kts+1 -> buf1 (B only;
    // A halves staged during iteration 0 at p0/p1).
    stage_half(gB,              65536u,           kts);
    stage_half(gB + 128 * KDIM, 65536u + 16384u,  kts);
    stage_half(gA,              0u,               kts);
    stage_half(gA + 128 * KDIM, 16384u,           kts);
    stage_half(gB,              65536u + 32768u,          kts + 1);
    stage_half(gB + 128 * KDIM, 65536u + 32768u + 16384u, kts + 1);
    asm volatile("s_waitcnt vmcnt(4)" ::: "memory");  // tile kts fully landed
    __builtin_amdgcn_s_barrier();

    s16x8 bb[4][2];
    for (int T = 0; T < cnt; ++T) {
      const uint32_t bo = (uint32_t)(T & 1) * 32768u;   // buf being read
      const uint32_t so = bo ^ 32768u;                  // buf of tile T+1 (idle)
      const bool stA = (T + 1 < cnt);
      const bool stB = (T + 2 < cnt);
      const int ktA = kts + T + 1;
      const int ktB = kts + T + 2;

      // ---- phase 0: read B(8) + a0,a1 ; stage A0(T+1) into idle buf ----
      {
        s16x8 ax[2][2];
#pragma unroll
        for (int n = 0; n < 4; n++) { bb[n][0] = rdB(bo, n, 0); bb[n][1] = rdB(bo, n, 1); }
#pragma unroll
        for (int m = 0; m < 2; m++) { ax[m][0] = rdA(bo, m, 0); ax[m][1] = rdA(bo, m, 1); }
        if (stA) stage_half(gA, so, ktA);
        __builtin_amdgcn_s_barrier();
        __builtin_amdgcn_s_setprio(1);
#pragma unroll
        for (int m = 0; m < 2; m++)
#pragma unroll
          for (int n = 0; n < 4; n++) {
            acc[m][n] = __builtin_amdgcn_mfma_f32_16x16x32_bf16(ax[m][0], bb[n][0], acc[m][n], 0, 0, 0);
            acc[m][n] = __builtin_amdgcn_mfma_f32_16x16x32_bf16(ax[m][1], bb[n][1], acc[m][n], 0, 0, 0);
          }
        __builtin_amdgcn_s_setprio(0);
        __builtin_amdgcn_s_barrier();
      }

      // ---- phase 1: read a2,a3 ; stage A1(T+1) ----
      {
        s16x8 ax[2][2];
#pragma unroll
        for (int m = 0; m < 2; m++) { ax[m][0] = rdA(bo, m + 2, 0); ax[m][1] = rdA(bo, m + 2, 1); }
        if (stA) stage_half(gA + 128 * KDIM, so + 16384u, ktA);
        __builtin_amdgcn_s_barrier();
        __builtin_amdgcn_s_setprio(1);
#pragma unroll
        for (int m = 0; m < 2; m++)
#pragma unroll
          for (int n = 0; n < 4; n++) {
            acc[m + 2][n] = __builtin_amdgcn_mfma_f32_16x16x32_bf16(ax[m][0], bb[n][0], acc[m + 2][n], 0, 0, 0);
            acc[m + 2][n] = __builtin_amdgcn_mfma_f32_16x16x32_bf16(ax[m][1], bb[n][1], acc[m + 2][n], 0, 0, 0);
          }
        __builtin_amdgcn_s_setprio(0);
        __builtin_amdgcn_s_barrier();
      }

      // ---- phase 2: read a4,a5 ; stage B0(T+2) into cur buf (B read at p0) ----
      {
        s16x8 ax[2][2];
#pragma unroll
        for (int m = 0; m < 2; m++) { ax[m][0] = rdA(bo, m + 4, 0); ax[m][1] = rdA(bo, m + 4, 1); }
        if (stB) stage_half(gB, 65536u + bo, ktB);
        __builtin_amdgcn_s_barrier();
        __builtin_amdgcn_s_setprio(1);
#pragma unroll
        for (int m = 0; m < 2; m++)
#pragma unroll
          for (int n = 0; n < 4; n++) {
            acc[m + 4][n] = __builtin_amdgcn_mfma_f32_16x16x32_bf16(ax[m][0], bb[n][0], acc[m + 4][n], 0, 0, 0);
            acc[m + 4][n] = __builtin_amdgcn_mfma_f32_16x16x32_bf16(ax[m][1], bb[n][1], acc[m + 4][n], 0, 0, 0);
          }
        __builtin_amdgcn_s_setprio(0);
        __builtin_amdgcn_s_barrier();
      }

      // ---- phase 3: read a6,a7 ; stage B1(T+2) ; counted vmcnt ----
      {
        s16x8 ax[2][2];
#pragma unroll
        for (int m = 0; m < 2; m++) { ax[m][0] = rdA(bo, m + 6, 0); ax[m][1] = rdA(bo, m + 6, 1); }
        if (stB) stage_half(gB + 128 * KDIM, 65536u + bo + 16384u, ktB);
        __builtin_amdgcn_s_barrier();
        __builtin_amdgcn_s_setprio(1);
#pragma unroll
        for (int m = 0; m < 2; m++)
#pragma unroll
          for (int n = 0; n < 4; n++) {
            acc[m + 6][n] = __builtin_amdgcn_mfma_f32_16x16x32_bf16(ax[m][0], bb[n][0], acc[m + 6][n], 0, 0, 0);
            acc[m + 6][n] = __builtin_amdgcn_mfma_f32_16x16x32_bf16(ax[m][1], bb[n][1], acc[m + 6][n], 0, 0, 0);
          }
        __builtin_amdgcn_s_setprio(0);
        // vmcnt(4): leaves only this iter's p2/p3 loads (B of T+2) in flight;
        // A(T+1) + all of T+1's B guaranteed landed before next p0 reads.
        if (stB) { asm volatile("s_waitcnt vmcnt(4)" ::: "memory"); }
        else     { asm volatile("s_waitcnt vmcnt(0)" ::: "memory"); }
        __builtin_amdgcn_s_barrier();
      }
    }

    // epilogue: tile-local 256x256 partial, non-atomic full write
    // C/D layout (m89): col = lane&15, row = (lane>>4)*4 + reg
    float* outp = pbuf + (size_t)pidx * 65536;
    const int r0 = wr * 128 + ((lane >> 4) << 2);
    const int c0 = wc * 64 + (lane & 15);
#pragma unroll
    for (int m = 0; m < 8; m++)
#pragma unroll
      for (int n = 0; n < 4; n++)
#pragma unroll
        for (int rg = 0; rg < 4; rg++)
          outp[(size_t)(r0 + m * 16 + rg) * 256 + (c0 + n * 16)] = acc[m][n][rg];
  }
}

// helpers: tile id from (ti<=tj)
__device__ __forceinline__ int tile_id(int ti, int tj) {
  return 4 * ti - ((ti * (ti - 1)) >> 1) + (tj - ti);
}

// ---- diag_n[i] = g[i][i] * inv_i^2 ----
__global__ void k_diag(const float* __restrict__ pbuf, const float* __restrict__ inv_norm,
                       float* __restrict__ diag) {
  const int i = blockIdx.x * 256 + threadIdx.x;
  const int ti = i >> 8;
  const int t = tile_id(ti, ti);
  const int b_lo = (KTPT * t + KTPB - 1) / KTPB;
  const int b_hi = (KTPT * (t + 1) + KTPB - 1) / KTPB - 1;
  const bool extra = ((KTPT * t) % KTPB) != 0;
  const int off = (i & 255) * 257;
  float s = 0.f;
  for (int p = b_lo; p <= b_hi; ++p) s += pbuf[(size_t)p * 65536 + off];
  if (extra) s += pbuf[(size_t)(256 + t) * 65536 + off];
  const float w = inv_norm[i];
  diag[i] = s * w * w;
}

// ---- accum = sum_{i<j} exp(-max(d_i + d_j - 2 g_ij inv_i inv_j, 0)) ----
__global__ void k_expsum(const float* __restrict__ pbuf, const float* __restrict__ inv_norm,
                         const float* __restrict__ diag, float* __restrict__ accum) {
  const int gid = blockIdx.x * 256 + threadIdx.x;
  const int e0 = gid * 4;
  const int i  = e0 >> 10;
  const int j0 = e0 & 1023;
  const int ti = i >> 8, tj = j0 >> 8;
  float s = 0.f;
  if (tj >= ti && j0 + 3 > i) {
    const int t = tile_id(ti, tj);
    const int b_lo = (KTPT * t + KTPB - 1) / KTPB;
    const int b_hi = (KTPT * (t + 1) + KTPB - 1) / KTPB - 1;
    const bool extra = ((KTPT * t) % KTPB) != 0;
    const int off = (i & 255) * 256 + (j0 & 255);
    float gx = 0.f, gy = 0.f, gz = 0.f, gw = 0.f;
    for (int p = b_lo; p <= b_hi; ++p) {
      const float4 v = *(const float4*)(pbuf + (size_t)p * 65536 + off);
      gx += v.x; gy += v.y; gz += v.z; gw += v.w;
    }
    if (extra) {
      const float4 v = *(const float4*)(pbuf + (size_t)(256 + t) * 65536 + off);
      gx += v.x; gy += v.y; gz += v.z; gw += v.w;
    }
    const float wi = inv_norm[i];
    const float di = diag[i];
    const float4 wj = *(const float4*)(inv_norm + j0);
    const float4 dj = *(const float4*)(diag + j0);
    float gn, d2;
    gn = gx * wi * wj.x; d2 = fmaxf(di + dj.x - 2.f * gn, 0.f); if (i < j0 + 0) s += expf(-d2);
    gn = gy * wi * wj.y; d2 = fmaxf(di + dj.y - 2.f * gn, 0.f); if (i < j0 + 1) s += expf(-d2);
    gn = gz * wi * wj.z; d2 = fmaxf(di + dj.z - 2.f * gn, 0.f); if (i < j0 + 2) s += expf(-d2);
    gn = gw * wi * wj.w; d2 = fmaxf(di + dj.w - 2.f * gn, 0.f); if (i < j0 + 3) s += expf(-d2);
  }
  for (int off = 32; off; off >>= 1) s += __shfl_down(s, off, 64);
  __shared__ float part[4];
  const int lane = threadIdx.x & 63, w = threadIdx.x >> 6;
  if (lane == 0) part[w] = s;
  __syncthreads();
  if (threadIdx.x == 0) atomicAdd(accum, part[0] + part[1] + part[2] + part[3]);
}

__global__ void k_final(const float* __restrict__ accum, float* __restrict__ out) {
  const float n_pairs = (float)NROWS * (float)(NROWS - 1) * 0.5f;
  out[0] = 0.25f * logf(accum[0] / n_pairs);
}

extern "C" void kernel_launch(void* const* d_in, const int* in_sizes, int n_in,
                              void* d_out, int out_size, void* d_ws, size_t ws_size,
                              hipStream_t stream) {
  const float* z = (const float*)d_in[0];
  float* out = (float*)d_out;
  char* ws = (char*)d_ws;

  // layout: inv_norm 4KB | diag 4KB | accum | ... | pbuf 68MB | zb 128MB
  float*  inv_norm = (float*)(ws);
  float*  diag     = (float*)(ws + 4096);
  float*  accum    = (float*)(ws + 8192);
  float*  pbuf     = (float*)(ws + 65536);
  ushort* zbuf     = (ushort*)(ws + 65536 + (size_t)PARTN * 65536 * sizeof(float));

  hipMemsetAsync(accum, 0, sizeof(float), stream);

  k_prep<<<NROWS, 256, 0, stream>>>(z, zbuf, inv_norm);

  hipFuncSetAttribute(reinterpret_cast<const void*>(&k_gram8),
                      hipFuncAttributeMaxDynamicSharedMemorySize, 131072);
  k_gram8<<<256, 512, 131072, stream>>>(zbuf, pbuf);

  k_diag<<<NROWS / 256, 256, 0, stream>>>(pbuf, inv_norm, diag);
  k_expsum<<<(NROWS * NROWS / 4) / 256, 256, 0, stream>>>(pbuf, inv_norm, diag, accum);
  k_final<<<1, 1, 0, stream>>>(accum, out);
}

// Round 6
// 295.702 us; speedup vs baseline: 1.1693x; 1.1037x over previous
//
#include <hip/hip_runtime.h>
#include <hip/hip_bf16.h>
#include <stdint.h>

// DispersiveLoss: B=1024 rows, D=65536.
// R6: single change vs R5 — pin register budget. R4/R5 spilled the 128-f32
// accumulator to scratch (WRITE_SIZE 179-186MB vs 68MB of real writes;
// VGPR_Count capped at 128): with dynamic LDS the backend's occupancy
// heuristic assumes LDS~0 and targets 4 waves/EU (128-reg budget).
// amdgpu_waves_per_eu(2,2) pins 2 waves/EU -> 256-reg budget (m69):
// acc->AGPR(128), frags+addr in VGPR, no spill. Schedule unchanged:
// race-free staggered 4-phase, 3-bit XOR swizzle, balanced 256-block
// symmetric (tile,K) decomposition, counted vmcnt(4).

#define NROWS 1024
#define KDIM  65536
#define BK    64
#define KTPT  1024        // K-tiles per tile: 65536/64
#define KTPB  40          // K-tiles per block: 10*1024/256
#define PARTN 266         // 256 block partials + 10 tile-crossing extras

typedef __attribute__((ext_vector_type(8))) short  s16x8;
typedef __attribute__((ext_vector_type(4))) float  f32x4;

#define AS1 __attribute__((address_space(1)))
#define AS3 __attribute__((address_space(3)))

__device__ __forceinline__ ushort f2bf(float f) {
  uint32_t u = __float_as_uint(f);
  return (ushort)((u + 0x7fffu + ((u >> 16) & 1u)) >> 16);  // RNE bf16
}

// ---- fused: row sum-of-squares -> inv_norm, plus raw fp32 -> bf16 cast ----
__global__ void k_prep(const float* __restrict__ z, ushort* __restrict__ zb,
                       float* __restrict__ inv_norm) {
  const int row = blockIdx.x;
  const float4* zr = (const float4*)(z + (size_t)row * KDIM);
  ushort* br = zb + (size_t)row * KDIM;
  float ss = 0.f;
  for (int i = threadIdx.x; i < KDIM / 4; i += blockDim.x) {
    const float4 v = zr[i];
    ss += v.x * v.x + v.y * v.y + v.z * v.z + v.w * v.w;
    ushort4 o;
    o.x = f2bf(v.x); o.y = f2bf(v.y); o.z = f2bf(v.z); o.w = f2bf(v.w);
    ((ushort4*)br)[i] = o;
  }
  for (int off = 32; off; off >>= 1) ss += __shfl_down(ss, off, 64);
  __shared__ float part[4];
  const int lane = threadIdx.x & 63, w = threadIdx.x >> 6;
  if (lane == 0) part[w] = ss;
  __syncthreads();
  if (threadIdx.x == 0) {
    const float t = part[0] + part[1] + part[2] + part[3];
    inv_norm[row] = 1.f / fmaxf(sqrtf(t), 1e-12f);
  }
}

// ---- 256^2 8-phase symmetric Gram, segmented K ----
// LDS (bytes): A[buf][half] = buf*32768 + half*16384 ; B = 65536 + same.
// Swizzle within a 128x64-bf16 half: P = L ^ (((L>>7)&7)<<4).
__global__
__attribute__((amdgpu_flat_work_group_size(512, 512), amdgpu_waves_per_eu(2, 2)))
void k_gram8(const ushort* __restrict__ zb, float* __restrict__ pbuf) {
  extern __shared__ char smem[];
  const int tid  = threadIdx.x;
  const int lane = tid & 63;
  const int wid  = tid >> 6;
  const int wr   = wid >> 2;     // 0..1  (M half)
  const int wc   = wid & 3;      // 0..3  (N quarter)

  const int b   = blockIdx.x;         // 0..255
  const int w0  = b * KTPB;
  const int t1  = w0 >> 10;
  const int kt0 = w0 & (KTPT - 1);
  const int n1  = min(KTPB, KTPT - kt0);
  const int nseg = (n1 < KTPB) ? 2 : 1;

  const uint32_t laneRB  = (uint32_t)(lane & 15) * 128u + (uint32_t)(lane >> 4) * 16u;
  const uint32_t aBase   = (uint32_t)wr * 16384u;
  const uint32_t bBase   = 65536u + (uint32_t)(wc >> 1) * 16384u;
  const uint32_t bRowOff = (uint32_t)(wc & 1) * 8192u;   // 64 rows * 128 B

  for (int seg = 0; seg < nseg; ++seg) {
    const int t    = (seg == 0) ? t1 : t1 + 1;
    const int kts  = (seg == 0) ? kt0 : 0;
    const int cnt  = (seg == 0) ? n1  : KTPB - n1;   // >= 16 always
    const int pidx = (seg == 0) ? b   : 256 + t;

    const int tm = (t < 4) ? 0 : (t < 7) ? 1 : (t < 9) ? 2 : 3;
    const int tbase = 4 * tm - ((tm * (tm - 1)) >> 1);
    const int tn = t - tbase + tm;

    const ushort* gA = zb + (size_t)(tm * 256) * KDIM;
    const ushort* gB = zb + (size_t)(tn * 256) * KDIM;

    // stage one 128x64 half-tile (16 KB): 2 x global_load_lds(16B)/thread.
    // LDS dest linear; global source pre-swizzled (involution).
    auto stage_half = [&](const ushort* halfPanel, uint32_t ldsHalfBase, int ktAbs) {
#pragma unroll
      for (int q = 0; q < 2; q++) {
        const uint32_t P = q * 8192u + (uint32_t)tid * 16u;
        const uint32_t L = P ^ (((P >> 7) & 7u) << 4);
        __builtin_amdgcn_global_load_lds(
            (const AS1 void*)((const char*)halfPanel + (size_t)(L >> 7) * (KDIM * 2)
                              + (L & 127u) + (size_t)ktAbs * (BK * 2)),
            (AS3 void*)(smem + ldsHalfBase + P), 16, 0, 0);
      }
    };
    auto rdA = [&](uint32_t bo, int mi, int kk) -> s16x8 {
      uint32_t L = laneRB + (uint32_t)mi * 2048u + (uint32_t)kk * 64u;
      uint32_t P = L ^ (((L >> 7) & 7u) << 4);
      return *(const s16x8*)(smem + aBase + bo + P);
    };
    auto rdB = [&](uint32_t bo, int ni, int kk) -> s16x8 {
      uint32_t L = bRowOff + laneRB + (uint32_t)ni * 2048u + (uint32_t)kk * 64u;
      uint32_t P = L ^ (((L >> 7) & 7u) << 4);
      return *(const s16x8*)(smem + bBase + bo + P);
    };

    f32x4 acc[8][4];
#pragma unroll
    for (int m = 0; m < 8; m++)
#pragma unroll
      for (int n = 0; n < 4; n++) acc[m][n] = (f32x4){0.f, 0.f, 0.f, 0.f};

    // prologue: tile kts -> buf0 (all 4 halves), tile kts+1 -> buf1 (B only;
    // A halves staged during iteration 0 at p0/p1).
    stage_half(gB,              65536u,           kts);
    stage_half(gB + 128 * KDIM, 65536u + 16384u,  kts);
    stage_half(gA,              0u,               kts);
    stage_half(gA + 128 * KDIM, 16384u,           kts);
    stage_half(gB,              65536u + 32768u,          kts + 1);
    stage_half(gB + 128 * KDIM, 65536u + 32768u + 16384u, kts + 1);
    asm volatile("s_waitcnt vmcnt(4)" ::: "memory");  // tile kts fully landed
    __builtin_amdgcn_s_barrier();

    s16x8 bb[4][2];
    for (int T = 0; T < cnt; ++T) {
      const uint32_t bo = (uint32_t)(T & 1) * 32768u;   // buf being read
      const uint32_t so = bo ^ 32768u;                  // buf of tile T+1 (idle)
      const bool stA = (T + 1 < cnt);
      const bool stB = (T + 2 < cnt);
      const int ktA = kts + T + 1;
      const int ktB = kts + T + 2;

      // ---- phase 0: read B(8) + a0,a1 ; stage A0(T+1) into idle buf ----
      {
        s16x8 ax[2][2];
#pragma unroll
        for (int n = 0; n < 4; n++) { bb[n][0] = rdB(bo, n, 0); bb[n][1] = rdB(bo, n, 1); }
#pragma unroll
        for (int m = 0; m < 2; m++) { ax[m][0] = rdA(bo, m, 0); ax[m][1] = rdA(bo, m, 1); }
        if (stA) stage_half(gA, so, ktA);
        __builtin_amdgcn_s_barrier();
        __builtin_amdgcn_s_setprio(1);
#pragma unroll
        for (int m = 0; m < 2; m++)
#pragma unroll
          for (int n = 0; n < 4; n++) {
            acc[m][n] = __builtin_amdgcn_mfma_f32_16x16x32_bf16(ax[m][0], bb[n][0], acc[m][n], 0, 0, 0);
            acc[m][n] = __builtin_amdgcn_mfma_f32_16x16x32_bf16(ax[m][1], bb[n][1], acc[m][n], 0, 0, 0);
          }
        __builtin_amdgcn_s_setprio(0);
        __builtin_amdgcn_s_barrier();
      }

      // ---- phase 1: read a2,a3 ; stage A1(T+1) ----
      {
        s16x8 ax[2][2];
#pragma unroll
        for (int m = 0; m < 2; m++) { ax[m][0] = rdA(bo, m + 2, 0); ax[m][1] = rdA(bo, m + 2, 1); }
        if (stA) stage_half(gA + 128 * KDIM, so + 16384u, ktA);
        __builtin_amdgcn_s_barrier();
        __builtin_amdgcn_s_setprio(1);
#pragma unroll
        for (int m = 0; m < 2; m++)
#pragma unroll
          for (int n = 0; n < 4; n++) {
            acc[m + 2][n] = __builtin_amdgcn_mfma_f32_16x16x32_bf16(ax[m][0], bb[n][0], acc[m + 2][n], 0, 0, 0);
            acc[m + 2][n] = __builtin_amdgcn_mfma_f32_16x16x32_bf16(ax[m][1], bb[n][1], acc[m + 2][n], 0, 0, 0);
          }
        __builtin_amdgcn_s_setprio(0);
        __builtin_amdgcn_s_barrier();
      }

      // ---- phase 2: read a4,a5 ; stage B0(T+2) into cur buf (B read at p0) ----
      {
        s16x8 ax[2][2];
#pragma unroll
        for (int m = 0; m < 2; m++) { ax[m][0] = rdA(bo, m + 4, 0); ax[m][1] = rdA(bo, m + 4, 1); }
        if (stB) stage_half(gB, 65536u + bo, ktB);
        __builtin_amdgcn_s_barrier();
        __builtin_amdgcn_s_setprio(1);
#pragma unroll
        for (int m = 0; m < 2; m++)
#pragma unroll
          for (int n = 0; n < 4; n++) {
            acc[m + 4][n] = __builtin_amdgcn_mfma_f32_16x16x32_bf16(ax[m][0], bb[n][0], acc[m + 4][n], 0, 0, 0);
            acc[m + 4][n] = __builtin_amdgcn_mfma_f32_16x16x32_bf16(ax[m][1], bb[n][1], acc[m + 4][n], 0, 0, 0);
          }
        __builtin_amdgcn_s_setprio(0);
        __builtin_amdgcn_s_barrier();
      }

      // ---- phase 3: read a6,a7 ; stage B1(T+2) ; counted vmcnt ----
      {
        s16x8 ax[2][2];
#pragma unroll
        for (int m = 0; m < 2; m++) { ax[m][0] = rdA(bo, m + 6, 0); ax[m][1] = rdA(bo, m + 6, 1); }
        if (stB) stage_half(gB + 128 * KDIM, 65536u + bo + 16384u, ktB);
        __builtin_amdgcn_s_barrier();
        __builtin_amdgcn_s_setprio(1);
#pragma unroll
        for (int m = 0; m < 2; m++)
#pragma unroll
          for (int n = 0; n < 4; n++) {
            acc[m + 6][n] = __builtin_amdgcn_mfma_f32_16x16x32_bf16(ax[m][0], bb[n][0], acc[m + 6][n], 0, 0, 0);
            acc[m + 6][n] = __builtin_amdgcn_mfma_f32_16x16x32_bf16(ax[m][1], bb[n][1], acc[m + 6][n], 0, 0, 0);
          }
        __builtin_amdgcn_s_setprio(0);
        // vmcnt(4): leaves only this iter's p2/p3 loads (B of T+2) in flight;
        // A(T+1) + B(T+1) guaranteed landed before next p0 reads them.
        if (stB) { asm volatile("s_waitcnt vmcnt(4)" ::: "memory"); }
        else     { asm volatile("s_waitcnt vmcnt(0)" ::: "memory"); }
        __builtin_amdgcn_s_barrier();
      }
    }

    // epilogue: tile-local 256x256 partial, non-atomic full write
    // C/D layout (m89): col = lane&15, row = (lane>>4)*4 + reg
    float* outp = pbuf + (size_t)pidx * 65536;
    const int r0 = wr * 128 + ((lane >> 4) << 2);
    const int c0 = wc * 64 + (lane & 15);
#pragma unroll
    for (int m = 0; m < 8; m++)
#pragma unroll
      for (int n = 0; n < 4; n++)
#pragma unroll
        for (int rg = 0; rg < 4; rg++)
          outp[(size_t)(r0 + m * 16 + rg) * 256 + (c0 + n * 16)] = acc[m][n][rg];
  }
}

// helpers: tile id from (ti<=tj)
__device__ __forceinline__ int tile_id(int ti, int tj) {
  return 4 * ti - ((ti * (ti - 1)) >> 1) + (tj - ti);
}

// ---- diag_n[i] = g[i][i] * inv_i^2 ----
__global__ void k_diag(const float* __restrict__ pbuf, const float* __restrict__ inv_norm,
                       float* __restrict__ diag) {
  const int i = blockIdx.x * 256 + threadIdx.x;
  const int ti = i >> 8;
  const int t = tile_id(ti, ti);
  const int b_lo = (KTPT * t + KTPB - 1) / KTPB;
  const int b_hi = (KTPT * (t + 1) + KTPB - 1) / KTPB - 1;
  const bool extra = ((KTPT * t) % KTPB) != 0;
  const int off = (i & 255) * 257;
  float s = 0.f;
  for (int p = b_lo; p <= b_hi; ++p) s += pbuf[(size_t)p * 65536 + off];
  if (extra) s += pbuf[(size_t)(256 + t) * 65536 + off];
  const float w = inv_norm[i];
  diag[i] = s * w * w;
}

// ---- accum = sum_{i<j} exp(-max(d_i + d_j - 2 g_ij inv_i inv_j, 0)) ----
__global__ void k_expsum(const float* __restrict__ pbuf, const float* __restrict__ inv_norm,
                         const float* __restrict__ diag, float* __restrict__ accum) {
  const int gid = blockIdx.x * 256 + threadIdx.x;
  const int e0 = gid * 4;
  const int i  = e0 >> 10;
  const int j0 = e0 & 1023;
  const int ti = i >> 8, tj = j0 >> 8;
  float s = 0.f;
  if (tj >= ti && j0 + 3 > i) {
    const int t = tile_id(ti, tj);
    const int b_lo = (KTPT * t + KTPB - 1) / KTPB;
    const int b_hi = (KTPT * (t + 1) + KTPB - 1) / KTPB - 1;
    const bool extra = ((KTPT * t) % KTPB) != 0;
    const int off = (i & 255) * 256 + (j0 & 255);
    float gx = 0.f, gy = 0.f, gz = 0.f, gw = 0.f;
    for (int p = b_lo; p <= b_hi; ++p) {
      const float4 v = *(const float4*)(pbuf + (size_t)p * 65536 + off);
      gx += v.x; gy += v.y; gz += v.z; gw += v.w;
    }
    if (extra) {
      const float4 v = *(const float4*)(pbuf + (size_t)(256 + t) * 65536 + off);
      gx += v.x; gy += v.y; gz += v.z; gw += v.w;
    }
    const float wi = inv_norm[i];
    const float di = diag[i];
    const float4 wj = *(const float4*)(inv_norm + j0);
    const float4 dj = *(const float4*)(diag + j0);
    float gn, d2;
    gn = gx * wi * wj.x; d2 = fmaxf(di + dj.x - 2.f * gn, 0.f); if (i < j0 + 0) s += expf(-d2);
    gn = gy * wi * wj.y; d2 = fmaxf(di + dj.y - 2.f * gn, 0.f); if (i < j0 + 1) s += expf(-d2);
    gn = gz * wi * wj.z; d2 = fmaxf(di + dj.z - 2.f * gn, 0.f); if (i < j0 + 2) s += expf(-d2);
    gn = gw * wi * wj.w; d2 = fmaxf(di + dj.w - 2.f * gn, 0.f); if (i < j0 + 3) s += expf(-d2);
  }
  for (int off = 32; off; off >>= 1) s += __shfl_down(s, off, 64);
  __shared__ float part[4];
  const int lane = threadIdx.x & 63, w = threadIdx.x >> 6;
  if (lane == 0) part[w] = s;
  __syncthreads();
  if (threadIdx.x == 0) atomicAdd(accum, part[0] + part[1] + part[2] + part[3]);
}

__global__ void k_final(const float* __restrict__ accum, float* __restrict__ out) {
  const float n_pairs = (float)NROWS * (float)(NROWS - 1) * 0.5f;
  out[0] = 0.25f * logf(accum[0] / n_pairs);
}

extern "C" void kernel_launch(void* const* d_in, const int* in_sizes, int n_in,
                              void* d_out, int out_size, void* d_ws, size_t ws_size,
                              hipStream_t stream) {
  const float* z = (const float*)d_in[0];
  float* out = (float*)d_out;
  char* ws = (char*)d_ws;

  // layout: inv_norm 4KB | diag 4KB | accum | ... | pbuf 68MB | zb 128MB
  float*  inv_norm = (float*)(ws);
  float*  diag     = (float*)(ws + 4096);
  float*  accum    = (float*)(ws + 8192);
  float*  pbuf     = (float*)(ws + 65536);
  ushort* zbuf     = (ushort*)(ws + 65536 + (size_t)PARTN * 65536 * sizeof(float));

  hipMemsetAsync(accum, 0, sizeof(float), stream);

  k_prep<<<NROWS, 256, 0, stream>>>(z, zbuf, inv_norm);

  hipFuncSetAttribute(reinterpret_cast<const void*>(&k_gram8),
                      hipFuncAttributeMaxDynamicSharedMemorySize, 131072);
  k_gram8<<<256, 512, 131072, stream>>>(zbuf, pbuf);

  k_diag<<<NROWS / 256, 256, 0, stream>>>(pbuf, inv_norm, diag);
  k_expsum<<<(NROWS * NROWS / 4) / 256, 256, 0, stream>>>(pbuf, inv_norm, diag, accum);
  k_final<<<1, 1, 0, stream>>>(accum, out);
}

// Round 7
// 287.531 us; speedup vs baseline: 1.2025x; 1.0284x over previous
//
#include <hip/hip_runtime.h>
#include <hip/hip_bf16.h>
#include <stdint.h>

// DispersiveLoss: B=1024 rows, D=65536.
// R7: register-pressure surgery on R6 (schedule/swizzle/decomposition
// unchanged). R4-R6 spilled (~105MB excess WRITE + ~130MB excess FETCH per
// dispatch): at 512 thr the 2-waves/EU unified budget is 256 regs; acc=128
// (AGPR) leaves 128 arch, and 16x 64-bit staging addrs + per-call swizzle
// math blew it. Fix via swizzle algebra:
//  - staging: (L>>7)&7 depends only on tid -> ONE per-thread u32 offset
//    vOff serves all 16 global_load_lds (panel/q/kt are uniform SGPR adds).
//  - ds_read: (L>>7)&7 == lane&7 -> laneSwz const; 4 addr regs
//    (vA0,vA1,vB0,vB1), kk via ^64, dbuf via per-iter ^32768 toggle,
//    mi*2048 folded into the compile-time ds offset immediate.

#define NROWS 1024
#define KDIM  65536
#define BK    64
#define KTPT  1024        // K-tiles per tile: 65536/64
#define KTPB  40          // K-tiles per block: 10*1024/256
#define PARTN 266         // 256 block partials + 10 tile-crossing extras

typedef __attribute__((ext_vector_type(8))) short  s16x8;
typedef __attribute__((ext_vector_type(4))) float  f32x4;

#define AS1 __attribute__((address_space(1)))
#define AS3 __attribute__((address_space(3)))

__device__ __forceinline__ ushort f2bf(float f) {
  uint32_t u = __float_as_uint(f);
  return (ushort)((u + 0x7fffu + ((u >> 16) & 1u)) >> 16);  // RNE bf16
}

// ---- fused: row sum-of-squares -> inv_norm, plus raw fp32 -> bf16 cast ----
__global__ void k_prep(const float* __restrict__ z, ushort* __restrict__ zb,
                       float* __restrict__ inv_norm) {
  const int row = blockIdx.x;
  const float4* zr = (const float4*)(z + (size_t)row * KDIM);
  ushort* br = zb + (size_t)row * KDIM;
  float ss = 0.f;
  for (int i = threadIdx.x; i < KDIM / 4; i += blockDim.x) {
    const float4 v = zr[i];
    ss += v.x * v.x + v.y * v.y + v.z * v.z + v.w * v.w;
    ushort4 o;
    o.x = f2bf(v.x); o.y = f2bf(v.y); o.z = f2bf(v.z); o.w = f2bf(v.w);
    ((ushort4*)br)[i] = o;
  }
  for (int off = 32; off; off >>= 1) ss += __shfl_down(ss, off, 64);
  __shared__ float part[4];
  const int lane = threadIdx.x & 63, w = threadIdx.x >> 6;
  if (lane == 0) part[w] = ss;
  __syncthreads();
  if (threadIdx.x == 0) {
    const float t = part[0] + part[1] + part[2] + part[3];
    inv_norm[row] = 1.f / fmaxf(sqrtf(t), 1e-12f);
  }
}

// ---- 256^2 8-phase symmetric Gram, segmented K ----
// LDS (bytes): A[buf][half] = buf*32768 + half*16384 ; B = 65536 + same.
// Swizzle within a 128x64-bf16 half: P = L ^ (((L>>7)&7)<<4).
__global__
__attribute__((amdgpu_flat_work_group_size(512, 512), amdgpu_waves_per_eu(2, 2)))
void k_gram8(const ushort* __restrict__ zb, float* __restrict__ pbuf) {
  extern __shared__ char smem[];
  const int tid  = threadIdx.x;
  const int lane = tid & 63;
  const int wid  = tid >> 6;
  const int wr   = wid >> 2;     // 0..1  (M half)
  const int wc   = wid & 3;      // 0..3  (N quarter)

  const int b   = blockIdx.x;         // 0..255
  const int w0  = b * KTPB;
  const int t1  = w0 >> 10;
  const int kt0 = w0 & (KTPT - 1);
  const int n1  = min(KTPB, KTPT - kt0);
  const int nseg = (n1 < KTPB) ? 2 : 1;

  // per-thread staging constant: global byte offset within a half-tile
  // (q=0, kt=0) after pre-swizzle. (Lt>>7)&7 depends only on tid.
  const uint32_t Pt   = (uint32_t)tid * 16u;
  const uint32_t Lt   = Pt ^ (((Pt >> 7) & 7u) << 4);
  const uint32_t vOff = (Lt >> 7) * (uint32_t)(KDIM * 2) + (Lt & 127u);

  // per-thread ds-read constant: swizzled lane base ((L>>7)&7 == lane&7)
  const uint32_t laneRB  = (uint32_t)(lane & 15) * 128u + (uint32_t)(lane >> 4) * 16u;
  const uint32_t laneSwz = laneRB ^ (((uint32_t)lane & 7u) << 4);

  const char* zbC = (const char*)zb;

  for (int seg = 0; seg < nseg; ++seg) {
    const int t    = (seg == 0) ? t1 : t1 + 1;
    const int kts  = (seg == 0) ? kt0 : 0;
    const int cnt  = (seg == 0) ? n1  : KTPB - n1;   // even, >= 16
    const int pidx = (seg == 0) ? b   : 256 + t;

    const int tm = (t < 4) ? 0 : (t < 7) ? 1 : (t < 9) ? 2 : 3;
    const int tbase = 4 * tm - ((tm * (tm - 1)) >> 1);
    const int tn = t - tbase + tm;

    // uniform panel row-byte bases (u32; zb is 128 MB)
    const uint32_t gA0 = (uint32_t)(tm * 256) * (uint32_t)(KDIM * 2);
    const uint32_t gA1 = gA0 + 128u * (uint32_t)(KDIM * 2);
    const uint32_t gB0 = (uint32_t)(tn * 256) * (uint32_t)(KDIM * 2);
    const uint32_t gB1 = gB0 + 128u * (uint32_t)(KDIM * 2);

    // stage one 128x64 half-tile (16 KB): 2 x global_load_lds(16B)/thread.
    // Per-lane part of both src and dest is a per-thread constant.
    auto stage_half = [&](uint32_t gRowByte, uint32_t ldsHalfBase, int ktAbs) {
      const uint32_t g0 = gRowByte + (uint32_t)ktAbs * 128u;
#pragma unroll
      for (int q = 0; q < 2; q++) {
        __builtin_amdgcn_global_load_lds(
            (const AS1 void*)(zbC + (g0 + (uint32_t)q * (64u * KDIM * 2u) + vOff)),
            (AS3 void*)(smem + (ldsHalfBase + (uint32_t)q * 8192u + Pt)), 16, 0, 0);
      }
    };

    // ds-read address regs: buf selected by ^32768 toggle, kk by the *1 reg
    uint32_t vA0 = laneSwz + (uint32_t)wr * 16384u;
    uint32_t vA1 = vA0 ^ 64u;
    uint32_t vB0 = laneSwz + 65536u + (uint32_t)(wc >> 1) * 16384u
                 + (uint32_t)(wc & 1) * 8192u;
    uint32_t vB1 = vB0 ^ 64u;

    auto rdA = [&](int mi, int kk) -> s16x8 {
      return *(const s16x8*)(smem + ((kk ? vA1 : vA0) + (uint32_t)(mi * 2048)));
    };
    auto rdB = [&](int ni, int kk) -> s16x8 {
      return *(const s16x8*)(smem + ((kk ? vB1 : vB0) + (uint32_t)(ni * 2048)));
    };

    f32x4 acc[8][4];
#pragma unroll
    for (int m = 0; m < 8; m++)
#pragma unroll
      for (int n = 0; n < 4; n++) acc[m][n] = (f32x4){0.f, 0.f, 0.f, 0.f};

    // prologue: tile kts -> buf0 (4 halves), tile kts+1 -> buf1 (B only;
    // A(kts+1) staged during iteration 0 at p0/p1).
    stage_half(gB0, 65536u,           kts);
    stage_half(gB1, 65536u + 16384u,  kts);
    stage_half(gA0, 0u,               kts);
    stage_half(gA1, 16384u,           kts);
    stage_half(gB0, 65536u + 32768u,           kts + 1);
    stage_half(gB1, 65536u + 32768u + 16384u,  kts + 1);
    asm volatile("s_waitcnt vmcnt(4)" ::: "memory");  // tile kts fully landed
    __builtin_amdgcn_s_barrier();

    s16x8 bb[4][2];
    for (int T = 0; T < cnt; ++T) {
      const uint32_t bo = (uint32_t)(T & 1) * 32768u;   // buf being read
      const uint32_t so = bo ^ 32768u;                  // buf of tile T+1
      const bool stA = (T + 1 < cnt);
      const bool stB = (T + 2 < cnt);
      const int ktA = kts + T + 1;
      const int ktB = kts + T + 2;

      // ---- phase 0: read B(8) + a0,a1 ; stage A0(T+1) into idle buf ----
      {
        s16x8 ax[2][2];
#pragma unroll
        for (int n = 0; n < 4; n++) { bb[n][0] = rdB(n, 0); bb[n][1] = rdB(n, 1); }
#pragma unroll
        for (int m = 0; m < 2; m++) { ax[m][0] = rdA(m, 0); ax[m][1] = rdA(m, 1); }
        if (stA) stage_half(gA0, so, ktA);
        __builtin_amdgcn_s_barrier();
        __builtin_amdgcn_s_setprio(1);
#pragma unroll
        for (int m = 0; m < 2; m++)
#pragma unroll
          for (int n = 0; n < 4; n++) {
            acc[m][n] = __builtin_amdgcn_mfma_f32_16x16x32_bf16(ax[m][0], bb[n][0], acc[m][n], 0, 0, 0);
            acc[m][n] = __builtin_amdgcn_mfma_f32_16x16x32_bf16(ax[m][1], bb[n][1], acc[m][n], 0, 0, 0);
          }
        __builtin_amdgcn_s_setprio(0);
        __builtin_amdgcn_s_barrier();
      }

      // ---- phase 1: read a2,a3 ; stage A1(T+1) ----
      {
        s16x8 ax[2][2];
#pragma unroll
        for (int m = 0; m < 2; m++) { ax[m][0] = rdA(m + 2, 0); ax[m][1] = rdA(m + 2, 1); }
        if (stA) stage_half(gA1, so + 16384u, ktA);
        __builtin_amdgcn_s_barrier();
        __builtin_amdgcn_s_setprio(1);
#pragma unroll
        for (int m = 0; m < 2; m++)
#pragma unroll
          for (int n = 0; n < 4; n++) {
            acc[m + 2][n] = __builtin_amdgcn_mfma_f32_16x16x32_bf16(ax[m][0], bb[n][0], acc[m + 2][n], 0, 0, 0);
            acc[m + 2][n] = __builtin_amdgcn_mfma_f32_16x16x32_bf16(ax[m][1], bb[n][1], acc[m + 2][n], 0, 0, 0);
          }
        __builtin_amdgcn_s_setprio(0);
        __builtin_amdgcn_s_barrier();
      }

      // ---- phase 2: read a4,a5 ; stage B0(T+2) into cur buf (B read at p0) ----
      {
        s16x8 ax[2][2];
#pragma unroll
        for (int m = 0; m < 2; m++) { ax[m][0] = rdA(m + 4, 0); ax[m][1] = rdA(m + 4, 1); }
        if (stB) stage_half(gB0, 65536u + bo, ktB);
        __builtin_amdgcn_s_barrier();
        __builtin_amdgcn_s_setprio(1);
#pragma unroll
        for (int m = 0; m < 2; m++)
#pragma unroll
          for (int n = 0; n < 4; n++) {
            acc[m + 4][n] = __builtin_amdgcn_mfma_f32_16x16x32_bf16(ax[m][0], bb[n][0], acc[m + 4][n], 0, 0, 0);
            acc[m + 4][n] = __builtin_amdgcn_mfma_f32_16x16x32_bf16(ax[m][1], bb[n][1], acc[m + 4][n], 0, 0, 0);
          }
        __builtin_amdgcn_s_setprio(0);
        __builtin_amdgcn_s_barrier();
      }

      // ---- phase 3: read a6,a7 ; stage B1(T+2) ; counted vmcnt ----
      {
        s16x8 ax[2][2];
#pragma unroll
        for (int m = 0; m < 2; m++) { ax[m][0] = rdA(m + 6, 0); ax[m][1] = rdA(m + 6, 1); }
        if (stB) stage_half(gB1, 65536u + bo + 16384u, ktB);
        __builtin_amdgcn_s_barrier();
        __builtin_amdgcn_s_setprio(1);
#pragma unroll
        for (int m = 0; m < 2; m++)
#pragma unroll
          for (int n = 0; n < 4; n++) {
            acc[m + 6][n] = __builtin_amdgcn_mfma_f32_16x16x32_bf16(ax[m][0], bb[n][0], acc[m + 6][n], 0, 0, 0);
            acc[m + 6][n] = __builtin_amdgcn_mfma_f32_16x16x32_bf16(ax[m][1], bb[n][1], acc[m + 6][n], 0, 0, 0);
          }
        __builtin_amdgcn_s_setprio(0);
        // vmcnt(4): leaves only B(T+2) in flight; A(T+1)+B(T+1) landed
        // before next p0 reads them.
        if (stB) { asm volatile("s_waitcnt vmcnt(4)" ::: "memory"); }
        else     { asm volatile("s_waitcnt vmcnt(0)" ::: "memory"); }
        __builtin_amdgcn_s_barrier();
      }

      // toggle double-buffer in the ds-read address regs
      vA0 ^= 32768u; vA1 ^= 32768u; vB0 ^= 32768u; vB1 ^= 32768u;
    }

    // epilogue: tile-local 256x256 partial, non-atomic full write
    // C/D layout (m89): col = lane&15, row = (lane>>4)*4 + reg
    float* outp = pbuf + (size_t)pidx * 65536;
    const int r0 = wr * 128 + ((lane >> 4) << 2);
    const int c0 = wc * 64 + (lane & 15);
#pragma unroll
    for (int m = 0; m < 8; m++)
#pragma unroll
      for (int n = 0; n < 4; n++)
#pragma unroll
        for (int rg = 0; rg < 4; rg++)
          outp[(size_t)(r0 + m * 16 + rg) * 256 + (c0 + n * 16)] = acc[m][n][rg];
  }
}

// helpers: tile id from (ti<=tj)
__device__ __forceinline__ int tile_id(int ti, int tj) {
  return 4 * ti - ((ti * (ti - 1)) >> 1) + (tj - ti);
}

// ---- diag_n[i] = g[i][i] * inv_i^2 ----
__global__ void k_diag(const float* __restrict__ pbuf, const float* __restrict__ inv_norm,
                       float* __restrict__ diag) {
  const int i = blockIdx.x * 256 + threadIdx.x;
  const int ti = i >> 8;
  const int t = tile_id(ti, ti);
  const int b_lo = (KTPT * t + KTPB - 1) / KTPB;
  const int b_hi = (KTPT * (t + 1) + KTPB - 1) / KTPB - 1;
  const bool extra = ((KTPT * t) % KTPB) != 0;
  const int off = (i & 255) * 257;
  float s = 0.f;
  for (int p = b_lo; p <= b_hi; ++p) s += pbuf[(size_t)p * 65536 + off];
  if (extra) s += pbuf[(size_t)(256 + t) * 65536 + off];
  const float w = inv_norm[i];
  diag[i] = s * w * w;
}

// ---- accum = sum_{i<j} exp(-max(d_i + d_j - 2 g_ij inv_i inv_j, 0)) ----
__global__ void k_expsum(const float* __restrict__ pbuf, const float* __restrict__ inv_norm,
                         const float* __restrict__ diag, float* __restrict__ accum) {
  const int gid = blockIdx.x * 256 + threadIdx.x;
  const int e0 = gid * 4;
  const int i  = e0 >> 10;
  const int j0 = e0 & 1023;
  const int ti = i >> 8, tj = j0 >> 8;
  float s = 0.f;
  if (tj >= ti && j0 + 3 > i) {
    const int t = tile_id(ti, tj);
    const int b_lo = (KTPT * t + KTPB - 1) / KTPB;
    const int b_hi = (KTPT * (t + 1) + KTPB - 1) / KTPB - 1;
    const bool extra = ((KTPT * t) % KTPB) != 0;
    const int off = (i & 255) * 256 + (j0 & 255);
    float gx = 0.f, gy = 0.f, gz = 0.f, gw = 0.f;
    for (int p = b_lo; p <= b_hi; ++p) {
      const float4 v = *(const float4*)(pbuf + (size_t)p * 65536 + off);
      gx += v.x; gy += v.y; gz += v.z; gw += v.w;
    }
    if (extra) {
      const float4 v = *(const float4*)(pbuf + (size_t)(256 + t) * 65536 + off);
      gx += v.x; gy += v.y; gz += v.z; gw += v.w;
    }
    const float wi = inv_norm[i];
    const float di = diag[i];
    const float4 wj = *(const float4*)(inv_norm + j0);
    const float4 dj = *(const float4*)(diag + j0);
    float gn, d2;
    gn = gx * wi * wj.x; d2 = fmaxf(di + dj.x - 2.f * gn, 0.f); if (i < j0 + 0) s += expf(-d2);
    gn = gy * wi * wj.y; d2 = fmaxf(di + dj.y - 2.f * gn, 0.f); if (i < j0 + 1) s += expf(-d2);
    gn = gz * wi * wj.z; d2 = fmaxf(di + dj.z - 2.f * gn, 0.f); if (i < j0 + 2) s += expf(-d2);
    gn = gw * wi * wj.w; d2 = fmaxf(di + dj.w - 2.f * gn, 0.f); if (i < j0 + 3) s += expf(-d2);
  }
  for (int off = 32; off; off >>= 1) s += __shfl_down(s, off, 64);
  __shared__ float part[4];
  const int lane = threadIdx.x & 63, w = threadIdx.x >> 6;
  if (lane == 0) part[w] = s;
  __syncthreads();
  if (threadIdx.x == 0) atomicAdd(accum, part[0] + part[1] + part[2] + part[3]);
}

__global__ void k_final(const float* __restrict__ accum, float* __restrict__ out) {
  const float n_pairs = (float)NROWS * (float)(NROWS - 1) * 0.5f;
  out[0] = 0.25f * logf(accum[0] / n_pairs);
}

extern "C" void kernel_launch(void* const* d_in, const int* in_sizes, int n_in,
                              void* d_out, int out_size, void* d_ws, size_t ws_size,
                              hipStream_t stream) {
  const float* z = (const float*)d_in[0];
  float* out = (float*)d_out;
  char* ws = (char*)d_ws;

  // layout: inv_norm 4KB | diag 4KB | accum | ... | pbuf 68MB | zb 128MB
  float*  inv_norm = (float*)(ws);
  float*  diag     = (float*)(ws + 4096);
  float*  accum    = (float*)(ws + 8192);
  float*  pbuf     = (float*)(ws + 65536);
  ushort* zbuf     = (ushort*)(ws + 65536 + (size_t)PARTN * 65536 * sizeof(float));

  hipMemsetAsync(accum, 0, sizeof(float), stream);

  k_prep<<<NROWS, 256, 0, stream>>>(z, zbuf, inv_norm);

  hipFuncSetAttribute(reinterpret_cast<const void*>(&k_gram8),
                      hipFuncAttributeMaxDynamicSharedMemorySize, 131072);
  k_gram8<<<256, 512, 131072, stream>>>(zbuf, pbuf);

  k_diag<<<NROWS / 256, 256, 0, stream>>>(pbuf, inv_norm, diag);
  k_expsum<<<(NROWS * NROWS / 4) / 256, 256, 0, stream>>>(pbuf, inv_norm, diag, accum);
  k_final<<<1, 1, 0, stream>>>(accum, out);
}

// Round 8
// 195.795 us; speedup vs baseline: 1.7660x; 1.4685x over previous
//
#include <hip/hip_runtime.h>
#include <hip/hip_bf16.h>
#include <stdint.h>

// DispersiveLoss: B=1024 rows, D=65536.
// R8: locality re-decomposition. R7's split-K gave concurrent blocks
// disjoint K-slices -> zero L2 reuse -> staging streamed from L3/HBM
// (needs ~26 TB/s, has ~10). Now: 250 blocks = 10 tiles x 25 K-chunks,
// one tile per block; bijective XCD swizzle co-locates all 10 tiles at
// the same K-range per XCD (panels shared through L2, ~5x reuse).
// GEMM schedule/swizzle/addressing identical to R7.

#define NROWS 1024
#define KDIM  65536
#define BK    64
#define NCHUNK 25         // K-chunks per tile
#define CHUNK0 41         // K-tiles per chunk (last chunk: 40)
#define PARTN  250        // 10 tiles * 25 chunks

typedef __attribute__((ext_vector_type(8))) short  s16x8;
typedef __attribute__((ext_vector_type(4))) float  f32x4;

#define AS1 __attribute__((address_space(1)))
#define AS3 __attribute__((address_space(3)))

__device__ __forceinline__ ushort f2bf(float f) {
  uint32_t u = __float_as_uint(f);
  return (ushort)((u + 0x7fffu + ((u >> 16) & 1u)) >> 16);  // RNE bf16
}

// ---- fused: row sum-of-squares -> inv_norm, plus raw fp32 -> bf16 cast ----
__global__ void k_prep(const float* __restrict__ z, ushort* __restrict__ zb,
                       float* __restrict__ inv_norm) {
  const int row = blockIdx.x;
  const float4* zr = (const float4*)(z + (size_t)row * KDIM);
  ushort* br = zb + (size_t)row * KDIM;
  float ss = 0.f;
  for (int i = threadIdx.x; i < KDIM / 4; i += blockDim.x) {
    const float4 v = zr[i];
    ss += v.x * v.x + v.y * v.y + v.z * v.z + v.w * v.w;
    ushort4 o;
    o.x = f2bf(v.x); o.y = f2bf(v.y); o.z = f2bf(v.z); o.w = f2bf(v.w);
    ((ushort4*)br)[i] = o;
  }
  for (int off = 32; off; off >>= 1) ss += __shfl_down(ss, off, 64);
  __shared__ float part[4];
  const int lane = threadIdx.x & 63, w = threadIdx.x >> 6;
  if (lane == 0) part[w] = ss;
  __syncthreads();
  if (threadIdx.x == 0) {
    const float t = part[0] + part[1] + part[2] + part[3];
    inv_norm[row] = 1.f / fmaxf(sqrtf(t), 1e-12f);
  }
}

// ---- 256^2 8-phase symmetric Gram, one (tile, K-chunk) per block ----
// LDS (bytes): A[buf][half] = buf*32768 + half*16384 ; B = 65536 + same.
// Swizzle within a 128x64-bf16 half: P = L ^ (((L>>7)&7)<<4).
__global__
__attribute__((amdgpu_flat_work_group_size(512, 512), amdgpu_waves_per_eu(2, 2)))
void k_gram8(const ushort* __restrict__ zb, float* __restrict__ pbuf) {
  extern __shared__ char smem[];
  const int tid  = threadIdx.x;
  const int lane = tid & 63;
  const int wid  = tid >> 6;
  const int wr   = wid >> 2;     // 0..1  (M half)
  const int wc   = wid & 3;      // 0..3  (N quarter)

  // bijective XCD swizzle inverse (n=250, q=31, r=2): physical blockIdx.x -> l
  // such that XCD x hosts a contiguous logical range (all 10 tiles, same K).
  const int d   = blockIdx.x;
  const int xcd = d & 7, idx = d >> 3;
  const int l   = (xcd < 2) ? xcd * 32 + idx : 64 + (xcd - 2) * 31 + idx;
  const int kc   = l / 10;        // 0..24
  const int tile = l - kc * 10;   // 0..9
  const int kts  = kc * CHUNK0;
  const int cnt  = (kc == NCHUNK - 1) ? 40 : CHUNK0;
  const int pidx = tile * NCHUNK + kc;

  const int tm = (tile < 4) ? 0 : (tile < 7) ? 1 : (tile < 9) ? 2 : 3;
  const int tbase = 4 * tm - ((tm * (tm - 1)) >> 1);
  const int tn = tile - tbase + tm;

  // per-thread staging constant: global byte offset within a half-tile
  // (q=0, kt=0) after pre-swizzle. (Lt>>7)&7 depends only on tid.
  const uint32_t Pt   = (uint32_t)tid * 16u;
  const uint32_t Lt   = Pt ^ (((Pt >> 7) & 7u) << 4);
  const uint32_t vOff = (Lt >> 7) * (uint32_t)(KDIM * 2) + (Lt & 127u);

  // per-thread ds-read constant: swizzled lane base ((L>>7)&7 == lane&7)
  const uint32_t laneRB  = (uint32_t)(lane & 15) * 128u + (uint32_t)(lane >> 4) * 16u;
  const uint32_t laneSwz = laneRB ^ (((uint32_t)lane & 7u) << 4);

  const char* zbC = (const char*)zb;

  // uniform panel row-byte bases
  const uint32_t gA0 = (uint32_t)(tm * 256) * (uint32_t)(KDIM * 2);
  const uint32_t gA1 = gA0 + 128u * (uint32_t)(KDIM * 2);
  const uint32_t gB0 = (uint32_t)(tn * 256) * (uint32_t)(KDIM * 2);
  const uint32_t gB1 = gB0 + 128u * (uint32_t)(KDIM * 2);

  // stage one 128x64 half-tile (16 KB): 2 x global_load_lds(16B)/thread.
  auto stage_half = [&](uint32_t gRowByte, uint32_t ldsHalfBase, int ktAbs) {
    const uint32_t g0 = gRowByte + (uint32_t)ktAbs * 128u;
#pragma unroll
    for (int q = 0; q < 2; q++) {
      __builtin_amdgcn_global_load_lds(
          (const AS1 void*)(zbC + (g0 + (uint32_t)q * (64u * KDIM * 2u) + vOff)),
          (AS3 void*)(smem + (ldsHalfBase + (uint32_t)q * 8192u + Pt)), 16, 0, 0);
    }
  };

  // ds-read address regs: buf selected by ^32768 toggle, kk by the *1 reg
  uint32_t vA0 = laneSwz + (uint32_t)wr * 16384u;
  uint32_t vA1 = vA0 ^ 64u;
  uint32_t vB0 = laneSwz + 65536u + (uint32_t)(wc >> 1) * 16384u
               + (uint32_t)(wc & 1) * 8192u;
  uint32_t vB1 = vB0 ^ 64u;

  auto rdA = [&](int mi, int kk) -> s16x8 {
    return *(const s16x8*)(smem + ((kk ? vA1 : vA0) + (uint32_t)(mi * 2048)));
  };
  auto rdB = [&](int ni, int kk) -> s16x8 {
    return *(const s16x8*)(smem + ((kk ? vB1 : vB0) + (uint32_t)(ni * 2048)));
  };

  f32x4 acc[8][4];
#pragma unroll
  for (int m = 0; m < 8; m++)
#pragma unroll
    for (int n = 0; n < 4; n++) acc[m][n] = (f32x4){0.f, 0.f, 0.f, 0.f};

  // prologue: tile kts -> buf0 (4 halves), tile kts+1 -> buf1 (B only;
  // A(kts+1) staged during iteration 0 at p0/p1).
  stage_half(gB0, 65536u,           kts);
  stage_half(gB1, 65536u + 16384u,  kts);
  stage_half(gA0, 0u,               kts);
  stage_half(gA1, 16384u,           kts);
  stage_half(gB0, 65536u + 32768u,           kts + 1);
  stage_half(gB1, 65536u + 32768u + 16384u,  kts + 1);
  asm volatile("s_waitcnt vmcnt(4)" ::: "memory");  // tile kts fully landed
  __builtin_amdgcn_s_barrier();

  s16x8 bb[4][2];
  for (int T = 0; T < cnt; ++T) {
    const uint32_t bo = (uint32_t)(T & 1) * 32768u;   // buf being read (unused var kept implicit)
    const uint32_t so = bo ^ 32768u;                  // buf of tile T+1
    const bool stA = (T + 1 < cnt);
    const bool stB = (T + 2 < cnt);
    const int ktA = kts + T + 1;
    const int ktB = kts + T + 2;

    // ---- phase 0: read B(8) + a0,a1 ; stage A0(T+1) into idle buf ----
    {
      s16x8 ax[2][2];
#pragma unroll
      for (int n = 0; n < 4; n++) { bb[n][0] = rdB(n, 0); bb[n][1] = rdB(n, 1); }
#pragma unroll
      for (int m = 0; m < 2; m++) { ax[m][0] = rdA(m, 0); ax[m][1] = rdA(m, 1); }
      if (stA) stage_half(gA0, so, ktA);
      __builtin_amdgcn_s_barrier();
      __builtin_amdgcn_s_setprio(1);
#pragma unroll
      for (int m = 0; m < 2; m++)
#pragma unroll
        for (int n = 0; n < 4; n++) {
          acc[m][n] = __builtin_amdgcn_mfma_f32_16x16x32_bf16(ax[m][0], bb[n][0], acc[m][n], 0, 0, 0);
          acc[m][n] = __builtin_amdgcn_mfma_f32_16x16x32_bf16(ax[m][1], bb[n][1], acc[m][n], 0, 0, 0);
        }
      __builtin_amdgcn_s_setprio(0);
      __builtin_amdgcn_s_barrier();
    }

    // ---- phase 1: read a2,a3 ; stage A1(T+1) ----
    {
      s16x8 ax[2][2];
#pragma unroll
      for (int m = 0; m < 2; m++) { ax[m][0] = rdA(m + 2, 0); ax[m][1] = rdA(m + 2, 1); }
      if (stA) stage_half(gA1, so + 16384u, ktA);
      __builtin_amdgcn_s_barrier();
      __builtin_amdgcn_s_setprio(1);
#pragma unroll
      for (int m = 0; m < 2; m++)
#pragma unroll
        for (int n = 0; n < 4; n++) {
          acc[m + 2][n] = __builtin_amdgcn_mfma_f32_16x16x32_bf16(ax[m][0], bb[n][0], acc[m + 2][n], 0, 0, 0);
          acc[m + 2][n] = __builtin_amdgcn_mfma_f32_16x16x32_bf16(ax[m][1], bb[n][1], acc[m + 2][n], 0, 0, 0);
        }
      __builtin_amdgcn_s_setprio(0);
      __builtin_amdgcn_s_barrier();
    }

    // ---- phase 2: read a4,a5 ; stage B0(T+2) into cur buf (B read at p0) ----
    {
      s16x8 ax[2][2];
#pragma unroll
      for (int m = 0; m < 2; m++) { ax[m][0] = rdA(m + 4, 0); ax[m][1] = rdA(m + 4, 1); }
      if (stB) stage_half(gB0, 65536u + bo, ktB);
      __builtin_amdgcn_s_barrier();
      __builtin_amdgcn_s_setprio(1);
#pragma unroll
      for (int m = 0; m < 2; m++)
#pragma unroll
        for (int n = 0; n < 4; n++) {
          acc[m + 4][n] = __builtin_amdgcn_mfma_f32_16x16x32_bf16(ax[m][0], bb[n][0], acc[m + 4][n], 0, 0, 0);
          acc[m + 4][n] = __builtin_amdgcn_mfma_f32_16x16x32_bf16(ax[m][1], bb[n][1], acc[m + 4][n], 0, 0, 0);
        }
      __builtin_amdgcn_s_setprio(0);
      __builtin_amdgcn_s_barrier();
    }

    // ---- phase 3: read a6,a7 ; stage B1(T+2) ; counted vmcnt ----
    {
      s16x8 ax[2][2];
#pragma unroll
      for (int m = 0; m < 2; m++) { ax[m][0] = rdA(m + 6, 0); ax[m][1] = rdA(m + 6, 1); }
      if (stB) stage_half(gB1, 65536u + bo + 16384u, ktB);
      __builtin_amdgcn_s_barrier();
      __builtin_amdgcn_s_setprio(1);
#pragma unroll
      for (int m = 0; m < 2; m++)
#pragma unroll
        for (int n = 0; n < 4; n++) {
          acc[m + 6][n] = __builtin_amdgcn_mfma_f32_16x16x32_bf16(ax[m][0], bb[n][0], acc[m + 6][n], 0, 0, 0);
          acc[m + 6][n] = __builtin_amdgcn_mfma_f32_16x16x32_bf16(ax[m][1], bb[n][1], acc[m + 6][n], 0, 0, 0);
        }
      __builtin_amdgcn_s_setprio(0);
      // vmcnt(4): leaves only B(T+2) in flight; A(T+1)+B(T+1) landed
      // before next p0 reads them.
      if (stB) { asm volatile("s_waitcnt vmcnt(4)" ::: "memory"); }
      else     { asm volatile("s_waitcnt vmcnt(0)" ::: "memory"); }
      __builtin_amdgcn_s_barrier();
    }

    // toggle double-buffer in the ds-read address regs
    vA0 ^= 32768u; vA1 ^= 32768u; vB0 ^= 32768u; vB1 ^= 32768u;
  }

  // epilogue: tile-local 256x256 partial, non-atomic full write
  // C/D layout (m89): col = lane&15, row = (lane>>4)*4 + reg
  float* outp = pbuf + (size_t)pidx * 65536;
  const int r0 = wr * 128 + ((lane >> 4) << 2);
  const int c0 = wc * 64 + (lane & 15);
#pragma unroll
  for (int m = 0; m < 8; m++)
#pragma unroll
    for (int n = 0; n < 4; n++)
#pragma unroll
      for (int rg = 0; rg < 4; rg++)
        outp[(size_t)(r0 + m * 16 + rg) * 256 + (c0 + n * 16)] = acc[m][n][rg];
}

// helpers: tile id from (ti<=tj)
__device__ __forceinline__ int tile_id(int ti, int tj) {
  return 4 * ti - ((ti * (ti - 1)) >> 1) + (tj - ti);
}

// ---- diag_n[i] = g[i][i] * inv_i^2 ----
__global__ void k_diag(const float* __restrict__ pbuf, const float* __restrict__ inv_norm,
                       float* __restrict__ diag) {
  const int i = blockIdx.x * 256 + threadIdx.x;
  const int ti = i >> 8;
  const int t = tile_id(ti, ti);
  const int off = (i & 255) * 257;
  float s = 0.f;
  for (int c = 0; c < NCHUNK; ++c)
    s += pbuf[(size_t)(t * NCHUNK + c) * 65536 + off];
  const float w = inv_norm[i];
  diag[i] = s * w * w;
}

// ---- accum = sum_{i<j} exp(-max(d_i + d_j - 2 g_ij inv_i inv_j, 0)) ----
__global__ void k_expsum(const float* __restrict__ pbuf, const float* __restrict__ inv_norm,
                         const float* __restrict__ diag, float* __restrict__ accum) {
  const int gid = blockIdx.x * 256 + threadIdx.x;
  const int e0 = gid * 4;
  const int i  = e0 >> 10;
  const int j0 = e0 & 1023;
  const int ti = i >> 8, tj = j0 >> 8;
  float s = 0.f;
  if (tj >= ti && j0 + 3 > i) {
    const int t = tile_id(ti, tj);
    const int off = (i & 255) * 256 + (j0 & 255);
    float gx = 0.f, gy = 0.f, gz = 0.f, gw = 0.f;
    for (int c = 0; c < NCHUNK; ++c) {
      const float4 v = *(const float4*)(pbuf + (size_t)(t * NCHUNK + c) * 65536 + off);
      gx += v.x; gy += v.y; gz += v.z; gw += v.w;
    }
    const float wi = inv_norm[i];
    const float di = diag[i];
    const float4 wj = *(const float4*)(inv_norm + j0);
    const float4 dj = *(const float4*)(diag + j0);
    float gn, d2;
    gn = gx * wi * wj.x; d2 = fmaxf(di + dj.x - 2.f * gn, 0.f); if (i < j0 + 0) s += expf(-d2);
    gn = gy * wi * wj.y; d2 = fmaxf(di + dj.y - 2.f * gn, 0.f); if (i < j0 + 1) s += expf(-d2);
    gn = gz * wi * wj.z; d2 = fmaxf(di + dj.z - 2.f * gn, 0.f); if (i < j0 + 2) s += expf(-d2);
    gn = gw * wi * wj.w; d2 = fmaxf(di + dj.w - 2.f * gn, 0.f); if (i < j0 + 3) s += expf(-d2);
  }
  for (int off = 32; off; off >>= 1) s += __shfl_down(s, off, 64);
  __shared__ float part[4];
  const int lane = threadIdx.x & 63, w = threadIdx.x >> 6;
  if (lane == 0) part[w] = s;
  __syncthreads();
  if (threadIdx.x == 0) atomicAdd(accum, part[0] + part[1] + part[2] + part[3]);
}

__global__ void k_final(const float* __restrict__ accum, float* __restrict__ out) {
  const float n_pairs = (float)NROWS * (float)(NROWS - 1) * 0.5f;
  out[0] = 0.25f * logf(accum[0] / n_pairs);
}

extern "C" void kernel_launch(void* const* d_in, const int* in_sizes, int n_in,
                              void* d_out, int out_size, void* d_ws, size_t ws_size,
                              hipStream_t stream) {
  const float* z = (const float*)d_in[0];
  float* out = (float*)d_out;
  char* ws = (char*)d_ws;

  // layout: inv_norm 4KB | diag 4KB | accum | ... | pbuf 62.5MB | zb 128MB
  float*  inv_norm = (float*)(ws);
  float*  diag     = (float*)(ws + 4096);
  float*  accum    = (float*)(ws + 8192);
  float*  pbuf     = (float*)(ws + 65536);
  ushort* zbuf     = (ushort*)(ws + 65536 + (size_t)PARTN * 65536 * sizeof(float));

  hipMemsetAsync(accum, 0, sizeof(float), stream);

  k_prep<<<NROWS, 256, 0, stream>>>(z, zbuf, inv_norm);

  hipFuncSetAttribute(reinterpret_cast<const void*>(&k_gram8),
                      hipFuncAttributeMaxDynamicSharedMemorySize, 131072);
  k_gram8<<<PARTN, 512, 131072, stream>>>(zbuf, pbuf);

  k_diag<<<NROWS / 256, 256, 0, stream>>>(pbuf, inv_norm, diag);
  k_expsum<<<(NROWS * NROWS / 4) / 256, 256, 0, stream>>>(pbuf, inv_norm, diag, accum);
  k_final<<<1, 1, 0, stream>>>(accum, out);
}